// Round 16
// baseline (77.671 us; speedup 1.0000x reference)
//
#include <hip/hip_runtime.h>
#include <hip/hip_bf16.h>
#include <math.h>

#define IN_FEAT 4096
#define OUT_FEAT 4096
#define NCOMP 256
#define BATCH 4096
#define TWO_PI_F 6.28318530717958647692f

typedef __attribute__((ext_vector_type(8))) short short8;
typedef __attribute__((ext_vector_type(8))) __bf16 bf16x8;
typedef __attribute__((ext_vector_type(4))) float f32x4;
typedef __attribute__((ext_vector_type(16))) float f32x16;

// round-to-nearest-even f32 -> bf16
__device__ __forceinline__ ushort f2b(float f) {
  union { float f; unsigned u; } v; v.f = f;
  unsigned r = (v.u + 0x7fffu + ((v.u >> 16) & 1u)) >> 16;
  return (ushort)r;
}

__device__ __forceinline__ float b2f(short s) {
  union { unsigned u; float f; } v; v.u = ((unsigned)(ushort)s) << 16;
  return v.f;
}

__device__ __forceinline__ bf16x8 ld_frag(const void* p) {
  short8 s = *(const short8*)p;
  return __builtin_bit_cast(bf16x8, s);
}

// native casts -> v_cvt_pk_bf16_f32 (RTNE)
__device__ __forceinline__ short8 cvt8s(float4 a, float4 b) {
  bf16x8 r;
  r[0] = (__bf16)a.x; r[1] = (__bf16)a.y; r[2] = (__bf16)a.z; r[3] = (__bf16)a.w;
  r[4] = (__bf16)b.x; r[5] = (__bf16)b.y; r[6] = (__bf16)b.z; r[7] = (__bf16)b.w;
  return __builtin_bit_cast(short8, r);
}

__device__ __forceinline__ void gload_lds16(const void* g, void* l) {
  __builtin_amdgcn_global_load_lds(
      (const __attribute__((address_space(1))) void*)g,
      (__attribute__((address_space(3))) void*)l, 16, 0, 0);
}

// ---------------------------------------------------------------- prep
__global__ __launch_bounds__(256) void prep_kernel(
    const float* __restrict__ mus, const float* __restrict__ lvs,
    const float* __restrict__ w,
    ushort* __restrict__ Gt, ushort* __restrict__ GoT) {
  int idx = blockIdx.x * 256 + threadIdx.x;
  if (idx < NCOMP * IN_FEAT) {
    int m = idx >> 12, i = idx & (IN_FEAT - 1);
    float v = expf(lvs[2 * m]);
    float d = (float)i * (1.0f / (IN_FEAT - 1)) - mus[2 * m];
    float g = expf(-d * d * (0.5f / v)) * rsqrtf(TWO_PI_F * v) * w[m];
    Gt[idx] = f2b(g);
  } else {
    idx -= NCOMP * IN_FEAT;
    int o = idx >> 8, m = idx & (NCOMP - 1);
    float v = expf(lvs[2 * m + 1]);
    float d = (float)o * (1.0f / (OUT_FEAT - 1)) - mus[2 * m + 1];
    float g = expf(-d * d * (0.5f / v)) * rsqrtf(TWO_PI_F * v);
    GoT[idx] = f2b(g);
  }
}

// ---------------------------------------------------------------- GEMM1
// Contiguous-x + chunked-B: Cpart[z][4096][256](bf16) = x[32-band,KR] @ Gt^T
// x[32][KR=1024] f32 read CONTIGUOUSLY (wave reads 2 KB of ONE row per
// instr-pair: 16 ADJACENT lines, DRAM-page friendly), cvt'd to bf16 into a
// row-XOR-swizzled 64 KB LDS tile, staged ONCE per block. B: R12-verbatim
// zero-conflict gload_lds panels, 32 KB chunks of 64 k, double-buffered;
// __syncthreads per chunk is safe (only the 4 L2-hot B DMAs outstanding,
// ~800 cy compute cover). 8 waves = 32r x 32n each: 8 MFMA + 8 ds_read_b128
// per chunk. Grid (128, NS) = 512 blocks.
template<int NS>
__global__ __launch_bounds__(512, 1) void gemm1_kernel(
    const float* __restrict__ x, const ushort* __restrict__ Gt,
    ushort* __restrict__ Cpart) {
  constexpr int KR = IN_FEAT / NS;   // 1024 at NS=4
  constexpr int NCH = KR / 64;       // 16 chunks
  __shared__ __align__(16) ushort xs[32 * (KR > 1024 ? 1024 : KR)];  // <=64 KB
  __shared__ __align__(16) ushort Bs[2 * 16384];                     // 64 KB
  const int tid = threadIdx.x, wid = tid >> 6, lane = tid & 63;
  const int l15 = lane & 15, q = lane >> 4;
  const int m0 = blockIdx.x * 32;
  const int kb0 = blockIdx.y * KR;

  // B staging (R12 verbatim addressing): 32 DMAs/chunk, 4/wave
  const int brow = lane >> 2;
  const int bsw = (((lane & 3) ^ ((lane >> 3) & 3)) << 3);  // ushort units

  #define STAGE_B(buf, kc)                                                   \
    _Pragma("unroll")                                                        \
    for (int i_ = 0; i_ < 4; ++i_) {                                         \
      int idx_ = wid * 4 + i_, seg_ = idx_ >> 4, nf_ = idx_ & 15;            \
      gload_lds16(&Gt[(size_t)(nf_ * 16 + brow) * IN_FEAT + kb0 +            \
                      (kc) * 64 + seg_ * 32 + bsw],                          \
                  &Bs[(buf) * 16384 + seg_ * 8192 + nf_ * 512]);             \
    }

  // issue first B chunk, then stage x (x loads hide under nothing yet, but
  // B DMAs overlap the x load latency)
  STAGE_B(0, 0)

  // ---- x stage: wave wid handles rows wid*4..+3, KR/512 passes of 2 KB.
  // Lane reads 32 B contiguous (2 float4); instruction pair covers a 2 KB
  // window of ONE row. Write: ds_write_b128 at 16 B/lane, row-XOR swizzle.
  {
    constexpr int NP = KR / 512;  // passes per row (2 at KR=1024)
    float4 F0[4 * NP], F1[4 * NP];
    #pragma unroll
    for (int i = 0; i < 4 * NP; ++i) {
      int r = wid * 4 + (i >> (NP == 2 ? 1 : 0)) % 4;  // row select
      int pass = (NP == 2) ? (i & 1) : (i & (NP - 1));
      // recompute cleanly:
      r = wid * 4 + i / NP;
      pass = i % NP;
      const float* src = &x[(size_t)(m0 + r) * IN_FEAT + kb0 + pass * 512 + lane * 8];
      F0[i] = *(const float4*)src;
      F1[i] = *(const float4*)(src + 4);
    }
    #pragma unroll
    for (int i = 0; i < 4 * NP; ++i) {
      int r = wid * 4 + i / NP;
      int pass = i % NP;
      int byte = (r * (KR * 2) + pass * 1024 + lane * 16) ^ ((r & 7) << 4);
      *(short8*)((char*)xs + byte) = cvt8s(F0[i], F1[i]);
    }
  }
  __syncthreads();

  f32x4 acc[2][2] = {};  // [mi][nj]
  const int fswz = (q << 4) ^ (((l15 >> 1) & 3) << 4);
  const int aswz0 = (l15 & 7) << 4;

  for (int kc = 0; kc < NCH; ++kc) {
    if (kc + 1 < NCH) STAGE_B((kc + 1) & 1, kc + 1)
    const char* bb = (const char*)Bs + (kc & 1) * 32768;
    #pragma unroll
    for (int ks = 0; ks < 2; ++ks) {
      const int kbyte = kc * 128 + ks * 64 + q * 16;
      bf16x8 a0 = ld_frag((const char*)xs +
                          (((l15) * (KR * 2)) + (kbyte ^ aswz0)));
      bf16x8 a1 = ld_frag((const char*)xs +
                          (((16 + l15) * (KR * 2)) + (kbyte ^ aswz0)));
      const char* sb = bb + ks * 16384;
      bf16x8 b0 = ld_frag(sb + ((wid * 2 + 0) * 16 + l15) * 64 + fswz);
      bf16x8 b1 = ld_frag(sb + ((wid * 2 + 1) * 16 + l15) * 64 + fswz);
      acc[0][0] = __builtin_amdgcn_mfma_f32_16x16x32_bf16(a0, b0, acc[0][0], 0, 0, 0);
      acc[0][1] = __builtin_amdgcn_mfma_f32_16x16x32_bf16(a0, b1, acc[0][1], 0, 0, 0);
      acc[1][0] = __builtin_amdgcn_mfma_f32_16x16x32_bf16(a1, b0, acc[1][0], 0, 0, 0);
      acc[1][1] = __builtin_amdgcn_mfma_f32_16x16x32_bf16(a1, b1, acc[1][1], 0, 0, 0);
    }
    __syncthreads();
  }
  #undef STAGE_B

  ushort* Cp = Cpart + (size_t)blockIdx.y * ((size_t)BATCH * NCOMP);
  #pragma unroll
  for (int mi = 0; mi < 2; ++mi)
    #pragma unroll
    for (int nj = 0; nj < 2; ++nj)
      #pragma unroll
      for (int r = 0; r < 4; ++r) {
        int row = m0 + mi * 16 + q * 4 + r;
        int col = wid * 32 + nj * 16 + l15;
        Cp[(size_t)row * NCOMP + col] = f2b(acc[mi][nj][r]);
      }
}

// ---------------------------------------------------------------- reduce
template<int NS>
__global__ __launch_bounds__(256) void reduce_kernel(ushort* __restrict__ Cp) {
  size_t i = ((size_t)blockIdx.x * 256 + threadIdx.x) * 8;
  float s[8] = {};
  #pragma unroll
  for (int p = 0; p < NS; ++p) {
    short8 v = *(const short8*)&Cp[(size_t)p * BATCH * NCOMP + i];
    #pragma unroll
    for (int e = 0; e < 8; ++e) s[e] += b2f(v[e]);
  }
  short8 hh;
  #pragma unroll
  for (int e = 0; e < 8; ++e) hh[e] = (short)f2b(s[e]);
  *(short8*)&Cp[i] = hh;
}

// ---------------------------------------------------------------- GEMM2
// out[4096][4096](f32) = (Cb @ GoT^T) * scale; 32x32x16 MFMA.
// BM=BN=128; wave owns 64x64 (2x2 frags). Stage=32k, dbuf 32 KB.
__global__ __launch_bounds__(256, 4) void gemm2_kernel(
    const ushort* __restrict__ Cb, const ushort* __restrict__ GoT,
    const float* __restrict__ w, float* __restrict__ out) {
  __shared__ __align__(16) ushort lds[2 * 8192];  // per buf: A 8 KB, B 8 KB
  const int tid = threadIdx.x, wid = tid >> 6, lane = tid & 63;
  const int m0 = blockIdx.y * 128, n0 = blockIdx.x * 128;
  const int wr = (wid >> 1) * 64, wc = (wid & 1) * 64;
  const int r32 = lane & 31, h = lane >> 5;

  float4 wv = *(const float4*)&w[lane * 4];
  float s = wv.x + wv.y + wv.z + wv.w;
  #pragma unroll
  for (int off = 32; off > 0; off >>= 1) s += __shfl_xor(s, off);
  const float scale = 1.0f / ((float)IN_FEAT * s);

  const int brow = lane >> 2;
  const int bswz = (((lane & 3) ^ ((lane >> 3) & 3)) << 3);
  const int sw0 = (h << 4) ^ (((r32 >> 1) & 3) << 4);

  f32x16 acc[2][2] = {};

  #define STAGE2(buf, k0)                                                    \
    _Pragma("unroll")                                                        \
    for (int q2 = 0; q2 < 2; ++q2) {                                         \
      int c = wid * 2 + q2;                                                  \
      int row = c * 16 + brow;                                               \
      gload_lds16(&Cb[(size_t)(m0 + row) * NCOMP + (k0) + bswz],             \
                  &lds[(buf) * 8192 + c * 512]);                             \
      gload_lds16(&GoT[(size_t)(n0 + row) * NCOMP + (k0) + bswz],            \
                  &lds[(buf) * 8192 + 4096 + c * 512]);                      \
    }

  STAGE2(0, 0)
  __syncthreads();

  for (int t = 0; t < 8; ++t) {
    if (t < 7) STAGE2((t + 1) & 1, (t + 1) * 32)
    const char* base = (const char*)lds + (t & 1) * 16384;
    const char* Bb = base + 8192;
    #pragma unroll
    for (int s2 = 0; s2 < 2; ++s2) {
      const int off = sw0 ^ (s2 << 5);
      bf16x8 a0 = ld_frag(base + (wr + r32) * 64 + off);
      bf16x8 a1 = ld_frag(base + (wr + 32 + r32) * 64 + off);
      bf16x8 b0 = ld_frag(Bb + (wc + r32) * 64 + off);
      bf16x8 b1 = ld_frag(Bb + (wc + 32 + r32) * 64 + off);
      acc[0][0] = __builtin_amdgcn_mfma_f32_32x32x16_bf16(a0, b0, acc[0][0], 0, 0, 0);
      acc[0][1] = __builtin_amdgcn_mfma_f32_32x32x16_bf16(a0, b1, acc[0][1], 0, 0, 0);
      acc[1][0] = __builtin_amdgcn_mfma_f32_32x32x16_bf16(a1, b0, acc[1][0], 0, 0, 0);
      acc[1][1] = __builtin_amdgcn_mfma_f32_32x32x16_bf16(a1, b1, acc[1][1], 0, 0, 0);
    }
    __syncthreads();
  }
  #undef STAGE2

  #pragma unroll
  for (int mi = 0; mi < 2; ++mi)
    #pragma unroll
    for (int nj = 0; nj < 2; ++nj)
      #pragma unroll
      for (int g = 0; g < 16; ++g) {
        int row = m0 + wr + mi * 32 + (g & 3) + 8 * (g >> 2) + 4 * h;
        int col = n0 + wc + nj * 32 + r32;
        out[(size_t)row * OUT_FEAT + col] = acc[mi][nj][g] * scale;
      }
}

// ---------------------------------------------------------------- launch
extern "C" void kernel_launch(void* const* d_in, const int* in_sizes, int n_in,
                              void* d_out, int out_size, void* d_ws, size_t ws_size,
                              hipStream_t stream) {
  const float* x   = (const float*)d_in[0];
  const float* mus = (const float*)d_in[1];
  const float* lvs = (const float*)d_in[2];
  const float* w   = (const float*)d_in[3];
  float* out = (float*)d_out;

  ushort* Gt  = (ushort*)d_ws;                      // [256][4096] bf16, 2 MiB
  ushort* GoT = Gt  + (size_t)NCOMP * IN_FEAT;      // [4096][256] bf16, 2 MiB
  ushort* Cpart = GoT + (size_t)OUT_FEAT * NCOMP;   // NS x 2 MiB; Cb = Cpart[0]

  const size_t MiB = 1024 * 1024;
  const bool split4 = ws_size >= 12 * MiB;

  prep_kernel<<<(NCOMP * IN_FEAT + OUT_FEAT * NCOMP) / 256, 256, 0, stream>>>(
      mus, lvs, w, Gt, GoT);

  if (split4) {
    gemm1_kernel<4><<<dim3(BATCH / 32, 4), 512, 0, stream>>>(x, Gt, Cpart);
    reduce_kernel<4><<<BATCH * NCOMP / 8 / 256, 256, 0, stream>>>(Cpart);
  } else {
    gemm1_kernel<4><<<dim3(BATCH / 32, 4), 512, 0, stream>>>(x, Gt, Cpart);
    reduce_kernel<4><<<BATCH * NCOMP / 8 / 256, 256, 0, stream>>>(Cpart);
  }

  gemm2_kernel<<<dim3(OUT_FEAT / 128, BATCH / 128), 256, 0, stream>>>(
      Cpart, GoT, w, out);
}

// Round 17
// 57.865 us; speedup vs baseline: 1.3423x; 1.3423x over previous
//
#include <hip/hip_runtime.h>
#include <hip/hip_bf16.h>
#include <math.h>

#define IN_FEAT 4096
#define OUT_FEAT 4096
#define NCOMP 256
#define BATCH 4096
#define TWO_PI_F 6.28318530717958647692f

typedef __attribute__((ext_vector_type(8))) short short8;
typedef __attribute__((ext_vector_type(8))) __bf16 bf16x8;
typedef __attribute__((ext_vector_type(4))) float f32x4;
typedef __attribute__((ext_vector_type(16))) float f32x16;

// round-to-nearest-even f32 -> bf16
__device__ __forceinline__ ushort f2b(float f) {
  union { float f; unsigned u; } v; v.f = f;
  unsigned r = (v.u + 0x7fffu + ((v.u >> 16) & 1u)) >> 16;
  return (ushort)r;
}

__device__ __forceinline__ float b2f(short s) {
  union { unsigned u; float f; } v; v.u = ((unsigned)(ushort)s) << 16;
  return v.f;
}

__device__ __forceinline__ bf16x8 ld_frag(const void* p) {
  short8 s = *(const short8*)p;
  return __builtin_bit_cast(bf16x8, s);
}

__device__ __forceinline__ ushort4 cvt4s(float4 a) {
  ushort4 h;
  h.x = f2b(a.x); h.y = f2b(a.y); h.z = f2b(a.z); h.w = f2b(a.w);
  return h;
}

__device__ __forceinline__ void gload_lds16(const void* g, void* l) {
  __builtin_amdgcn_global_load_lds(
      (const __attribute__((address_space(1))) void*)g,
      (__attribute__((address_space(3))) void*)l, 16, 0, 0);
}

// ---------------------------------------------------------------- prep
__global__ __launch_bounds__(256) void prep_kernel(
    const float* __restrict__ mus, const float* __restrict__ lvs,
    const float* __restrict__ w,
    ushort* __restrict__ Gt, ushort* __restrict__ GoT) {
  int idx = blockIdx.x * 256 + threadIdx.x;
  if (idx < NCOMP * IN_FEAT) {
    int m = idx >> 12, i = idx & (IN_FEAT - 1);
    float v = expf(lvs[2 * m]);
    float d = (float)i * (1.0f / (IN_FEAT - 1)) - mus[2 * m];
    float g = expf(-d * d * (0.5f / v)) * rsqrtf(TWO_PI_F * v) * w[m];
    Gt[idx] = f2b(g);
  } else {
    idx -= NCOMP * IN_FEAT;
    int o = idx >> 8, m = idx & (NCOMP - 1);
    float v = expf(lvs[2 * m + 1]);
    float d = (float)o * (1.0f / (OUT_FEAT - 1)) - mus[2 * m + 1];
    float g = expf(-d * d * (0.5f / v)) * rsqrtf(TWO_PI_F * v);
    GoT[idx] = f2b(g);
  }
}

// ---------------------------------------------------------------- GEMM1
// Pipelined contiguous-x: Cpart[z][4096][256](bf16) = x[64-band, KR] @ Gt^T
// x staged in 64-k windows (16 KB f32): ONE dwordx4/thread, 4 rows x 256 B
// CONTIGUOUS per instruction (page-friendly), cvt->bf16, swizzled ds_write,
// double-buffered, issued 2 windows ahead (T14). B: R15's zero-conflict
// gload_lds chunks (64 k = 32 KB), double-buffered. Counted-vmcnt ledger
// per sub-chunk: issue B(4)+W(2) -> compute -> vmcnt(6) [W landed] ->
// ds_write -> vmcnt(2)+lgkmcnt(0) [B landed, next W flying] -> s_barrier.
// Never drains in-loop. LDS 80 KB -> 2 blocks/CU. 8 waves = 16r x 128n.
template<int NS>
__global__ __launch_bounds__(512, 2) void gemm1_kernel(
    const float* __restrict__ x, const ushort* __restrict__ Gt,
    ushort* __restrict__ Cpart) {
  constexpr int KR = IN_FEAT / NS;
  constexpr int NCH = KR / 64;  // sub-chunks / windows
  __shared__ __align__(16) ushort Bs[2 * 16384];  // 64 KB (2 x 32 KB)
  __shared__ __align__(16) ushort xs[2 * 4096];   // 16 KB (2 x 8 KB)
  const int tid = threadIdx.x, wid = tid >> 6, lane = tid & 63;
  const int l15 = lane & 15, q = lane >> 4;
  const int rg = wid >> 1, h2 = wid & 1;
  const int m0 = blockIdx.x * 64;
  const int kb0 = blockIdx.y * KR;

  // B staging (verified zero-conflict pair)
  const int brow = lane >> 2;
  const int bsw = (((lane & 3) ^ ((lane >> 3) & 3)) << 3);  // ushort units
  const int fswz = (q << 4) ^ (((l15 >> 1) & 3) << 4);      // bytes

  // x staging: rows xrow, xrow+32; thread = one float4 slot of a 256B row-seg
  const int xrow = tid >> 4, xslot = tid & 15;
  const float* xsrc0 = &x[(size_t)(m0 + xrow) * IN_FEAT + kb0 + xslot * 4];
  const float* xsrc1 = xsrc0 + (size_t)32 * IN_FEAT;
  const int wb0 = xrow * 128 + ((((xslot >> 1) ^ (xrow & 7)) << 4) | ((xslot & 1) << 3));
  const int wb1 = (xrow + 32) * 128 +
                  ((((xslot >> 1) ^ ((xrow + 32) & 7)) << 4) | ((xslot & 1) << 3));

  // A fragment read
  const int arow = rg * 16 + l15;
  const int akey = arow & 7;

  f32x4 acc[8] = {};
  float4 Pa0, Pa1, Pb0, Pb1;  // two windows in flight (even->Pa, odd->Pb)

  #define STAGE_B(buf, kc)                                                   \
    _Pragma("unroll")                                                        \
    for (int i_ = 0; i_ < 4; ++i_) {                                         \
      int idx_ = wid * 4 + i_, seg_ = idx_ >> 4, nf_ = idx_ & 15;            \
      gload_lds16(&Gt[(size_t)(nf_ * 16 + brow) * IN_FEAT + kb0 +            \
                      (kc) * 64 + seg_ * 32 + bsw],                          \
                  &Bs[(buf) * 16384 + seg_ * 8192 + nf_ * 512]);             \
    }

  #define LOAD_W(P0, P1, wn)                                                 \
    P0 = *(const float4*)(xsrc0 + (wn) * 64);                                \
    P1 = *(const float4*)(xsrc1 + (wn) * 64);

  #define WRITE_W(P0, P1, buf) {                                             \
    char* xb_ = (char*)xs + (buf) * 8192;                                    \
    *(ushort4*)(xb_ + wb0) = cvt4s(P0);                                      \
    *(ushort4*)(xb_ + wb1) = cvt4s(P1);                                      \
  }

  #define COMPUTE(kc) {                                                      \
    const char* Xb = (const char*)xs + ((kc) & 1) * 8192;                    \
    const char* Bb = (const char*)Bs + ((kc) & 1) * 32768;                   \
    _Pragma("unroll")                                                        \
    for (int st = 0; st < 2; ++st) {                                         \
      bf16x8 a = ld_frag(Xb + arow * 128 + (((st * 4 + q) ^ akey) << 4));    \
      const char* sb = Bb + st * 16384;                                      \
      _Pragma("unroll")                                                      \
      for (int j = 0; j < 8; ++j) {                                          \
        bf16x8 b = ld_frag(sb + ((h2 * 8 + j) * 16 + l15) * 64 + fswz);      \
        acc[j] = __builtin_amdgcn_mfma_f32_16x16x32_bf16(a, b, acc[j], 0, 0, 0); \
      }                                                                      \
    } }

  // ---- prologue: B0 + W0 + W1 in flight; X[0] written synchronously
  STAGE_B(0, 0)
  LOAD_W(Pa0, Pa1, 0)
  LOAD_W(Pb0, Pb1, 1)
  asm volatile("s_waitcnt vmcnt(2)" ::: "memory");  // B0 + W0 landed
  __builtin_amdgcn_sched_barrier(0);
  WRITE_W(Pa0, Pa1, 0)
  asm volatile("s_waitcnt lgkmcnt(0)" ::: "memory");
  __builtin_amdgcn_s_barrier();
  __builtin_amdgcn_sched_barrier(0);

  // ---- main loop: entering kc, ledger = [W(kc+1):2]
  #pragma unroll
  for (int kc = 0; kc < NCH; ++kc) {
    if (kc < NCH - 1) {
      STAGE_B((kc + 1) & 1, kc + 1)   // +4 -> [W:2][B:4]
      int wn = (kc + 2 < NCH) ? (kc + 2) : (NCH - 1);  // clamp keeps counts
      if ((kc & 1) == 0) { LOAD_W(Pa0, Pa1, wn) }      // +2 -> [W:2][B:4][W':2]
      else              { LOAD_W(Pb0, Pb1, wn) }
    }
    COMPUTE(kc)
    if (kc < NCH - 1) {
      asm volatile("s_waitcnt vmcnt(6)" ::: "memory");  // W(kc+1) landed
      __builtin_amdgcn_sched_barrier(0);
      if ((kc & 1) == 0) { WRITE_W(Pb0, Pb1, 1) }   // window kc+1 (odd)
      else              { WRITE_W(Pa0, Pa1, 0) }    // window kc+1 (even)
      asm volatile("s_waitcnt vmcnt(2) lgkmcnt(0)" ::: "memory");  // B landed
      __builtin_amdgcn_s_barrier();
      __builtin_amdgcn_sched_barrier(0);
    }
  }
  #undef STAGE_B
  #undef LOAD_W
  #undef WRITE_W
  #undef COMPUTE

  ushort* Cp = Cpart + (size_t)blockIdx.y * ((size_t)BATCH * NCOMP);
  #pragma unroll
  for (int j = 0; j < 8; ++j)
    #pragma unroll
    for (int r = 0; r < 4; ++r) {
      int row = m0 + rg * 16 + q * 4 + r;
      int col = h2 * 128 + j * 16 + l15;
      Cp[(size_t)row * NCOMP + col] = f2b(acc[j][r]);
    }
}

// ---------------------------------------------------------------- reduce
template<int NS>
__global__ __launch_bounds__(256) void reduce_kernel(ushort* __restrict__ Cp) {
  size_t i = ((size_t)blockIdx.x * 256 + threadIdx.x) * 8;
  float s[8] = {};
  #pragma unroll
  for (int p = 0; p < NS; ++p) {
    short8 v = *(const short8*)&Cp[(size_t)p * BATCH * NCOMP + i];
    #pragma unroll
    for (int e = 0; e < 8; ++e) s[e] += b2f(v[e]);
  }
  short8 hh;
  #pragma unroll
  for (int e = 0; e < 8; ++e) hh[e] = (short)f2b(s[e]);
  *(short8*)&Cp[i] = hh;
}

// ---------------------------------------------------------------- GEMM2
// out[4096][4096](f32) = (Cb @ GoT^T) * scale; 32x32x16 MFMA.
// BM=BN=128; wave owns 64x64 (2x2 frags). Stage=32k, dbuf 32 KB.
__global__ __launch_bounds__(256, 4) void gemm2_kernel(
    const ushort* __restrict__ Cb, const ushort* __restrict__ GoT,
    const float* __restrict__ w, float* __restrict__ out) {
  __shared__ __align__(16) ushort lds[2 * 8192];  // per buf: A 8 KB, B 8 KB
  const int tid = threadIdx.x, wid = tid >> 6, lane = tid & 63;
  const int m0 = blockIdx.y * 128, n0 = blockIdx.x * 128;
  const int wr = (wid >> 1) * 64, wc = (wid & 1) * 64;
  const int r32 = lane & 31, h = lane >> 5;

  float4 wv = *(const float4*)&w[lane * 4];
  float s = wv.x + wv.y + wv.z + wv.w;
  #pragma unroll
  for (int off = 32; off > 0; off >>= 1) s += __shfl_xor(s, off);
  const float scale = 1.0f / ((float)IN_FEAT * s);

  const int brow = lane >> 2;
  const int bswz = (((lane & 3) ^ ((lane >> 3) & 3)) << 3);
  const int sw0 = (h << 4) ^ (((r32 >> 1) & 3) << 4);

  f32x16 acc[2][2] = {};

  #define STAGE2(buf, k0)                                                    \
    _Pragma("unroll")                                                        \
    for (int q2 = 0; q2 < 2; ++q2) {                                         \
      int c = wid * 2 + q2;                                                  \
      int row = c * 16 + brow;                                               \
      gload_lds16(&Cb[(size_t)(m0 + row) * NCOMP + (k0) + bswz],             \
                  &lds[(buf) * 8192 + c * 512]);                             \
      gload_lds16(&GoT[(size_t)(n0 + row) * NCOMP + (k0) + bswz],            \
                  &lds[(buf) * 8192 + 4096 + c * 512]);                      \
    }

  STAGE2(0, 0)
  __syncthreads();

  for (int t = 0; t < 8; ++t) {
    if (t < 7) STAGE2((t + 1) & 1, (t + 1) * 32)
    const char* base = (const char*)lds + (t & 1) * 16384;
    const char* Bb = base + 8192;
    #pragma unroll
    for (int s2 = 0; s2 < 2; ++s2) {
      const int off = sw0 ^ (s2 << 5);
      bf16x8 a0 = ld_frag(base + (wr + r32) * 64 + off);
      bf16x8 a1 = ld_frag(base + (wr + 32 + r32) * 64 + off);
      bf16x8 b0 = ld_frag(Bb + (wc + r32) * 64 + off);
      bf16x8 b1 = ld_frag(Bb + (wc + 32 + r32) * 64 + off);
      acc[0][0] = __builtin_amdgcn_mfma_f32_32x32x16_bf16(a0, b0, acc[0][0], 0, 0, 0);
      acc[0][1] = __builtin_amdgcn_mfma_f32_32x32x16_bf16(a0, b1, acc[0][1], 0, 0, 0);
      acc[1][0] = __builtin_amdgcn_mfma_f32_32x32x16_bf16(a1, b0, acc[1][0], 0, 0, 0);
      acc[1][1] = __builtin_amdgcn_mfma_f32_32x32x16_bf16(a1, b1, acc[1][1], 0, 0, 0);
    }
    __syncthreads();
  }
  #undef STAGE2

  #pragma unroll
  for (int mi = 0; mi < 2; ++mi)
    #pragma unroll
    for (int nj = 0; nj < 2; ++nj)
      #pragma unroll
      for (int g = 0; g < 16; ++g) {
        int row = m0 + wr + mi * 32 + (g & 3) + 8 * (g >> 2) + 4 * h;
        int col = n0 + wc + nj * 32 + r32;
        out[(size_t)row * OUT_FEAT + col] = acc[mi][nj][g] * scale;
      }
}

// ---------------------------------------------------------------- launch
extern "C" void kernel_launch(void* const* d_in, const int* in_sizes, int n_in,
                              void* d_out, int out_size, void* d_ws, size_t ws_size,
                              hipStream_t stream) {
  const float* x   = (const float*)d_in[0];
  const float* mus = (const float*)d_in[1];
  const float* lvs = (const float*)d_in[2];
  const float* w   = (const float*)d_in[3];
  float* out = (float*)d_out;

  ushort* Gt  = (ushort*)d_ws;                      // [256][4096] bf16, 2 MiB
  ushort* GoT = Gt  + (size_t)NCOMP * IN_FEAT;      // [4096][256] bf16, 2 MiB
  ushort* Cpart = GoT + (size_t)OUT_FEAT * NCOMP;   // NS x 2 MiB; Cb = Cpart[0]

  const size_t MiB = 1024 * 1024;
  int nsplit = 8;
  while (nsplit > 1 && ws_size < 4 * MiB + (size_t)nsplit * 2 * MiB + MiB)
    nsplit >>= 1;

  prep_kernel<<<(NCOMP * IN_FEAT + OUT_FEAT * NCOMP) / 256, 256, 0, stream>>>(
      mus, lvs, w, Gt, GoT);

  switch (nsplit) {
    case 8:
      gemm1_kernel<8><<<dim3(BATCH / 64, 8), 512, 0, stream>>>(x, Gt, Cpart);
      reduce_kernel<8><<<BATCH * NCOMP / 8 / 256, 256, 0, stream>>>(Cpart);
      break;
    case 4:
      gemm1_kernel<4><<<dim3(BATCH / 64, 4), 512, 0, stream>>>(x, Gt, Cpart);
      reduce_kernel<4><<<BATCH * NCOMP / 8 / 256, 256, 0, stream>>>(Cpart);
      break;
    case 2:
      gemm1_kernel<2><<<dim3(BATCH / 64, 2), 512, 0, stream>>>(x, Gt, Cpart);
      reduce_kernel<2><<<BATCH * NCOMP / 8 / 256, 256, 0, stream>>>(Cpart);
      break;
    default:
      gemm1_kernel<1><<<dim3(BATCH / 64, 1), 512, 0, stream>>>(x, Gt, Cpart);
      break;
  }

  gemm2_kernel<<<dim3(OUT_FEAT / 128, BATCH / 128), 256, 0, stream>>>(
      Cpart, GoT, w, out);
}